// Round 1
// baseline (7556.509 us; speedup 1.0000x reference)
//
#include <hip/hip_runtime.h>
#include <stdint.h>

#define EPS 1e-5f

// ---------------- workspace layout (bytes) ----------------
#define OFF_W2R   0ULL                        // [576][128] f32      = 294912
#define OFF_W3R   (OFF_W2R + 294912ULL)       // [1152][256] f32     = 1179648
#define OFF_S1M   (OFF_W3R + 1179648ULL)      // [8][128][32][32] u64 = 8388608
#define OFF_S2PM  (OFF_S1M + 8388608ULL)      // [8][128][16][16][4] u32 = 4194304
#define OFF_V2    (OFF_S2PM + 4194304ULL)     // [128][128][32][32] f32 = 67108864
#define OFF_V3    (OFF_V2 + 67108864ULL)      // [128][256][16][16] f32 = 33554432
#define OFF_S3F   (OFF_V3 + 33554432ULL)      // [8][128][16384] f32 = 67108864
#define OFF_PRE4  (OFF_S3F + 67108864ULL)     // [1024][512] f32     = 2097152
#define OFF_FEAT  (OFF_PRE4 + 2097152ULL)     // [128][512] f32      = 262144
#define OFF_PN    (OFF_FEAT + 262144ULL)      // [10][512] f32       = 20480

// ---------------- weight repack: [oc][ic][3][3] -> [ic*9+tap][oc] ----------------
__global__ void repack_w2(const float* __restrict__ w2, float* __restrict__ w2r) {
    int i = blockIdx.x * 256 + threadIdx.x;           // 128*64*9 = 73728
    if (i >= 73728) return;
    int oc = i / 576, r = i % 576;
    w2r[r * 128 + oc] = w2[i];
}
__global__ void repack_w3(const float* __restrict__ w3, float* __restrict__ w3r) {
    int i = blockIdx.x * 256 + threadIdx.x;           // 256*128*9 = 294912
    if (i >= 294912) return;
    int oc = i / 1152, r = i % 1152;
    w3r[r * 256 + oc] = w3[i];
}

// ---------------- conv1 + BN + LIF (t-loop inside, v in registers) ----------------
// wave = one pixel, lane = oc (64 oc exactly). Spikes packed via ballot.
__global__ __launch_bounds__(256) void conv1_lif_pack(
    const float* __restrict__ x,          // [8][128][3][32][32]
    const float* __restrict__ w1,         // [64][3][3][3]
    const float* __restrict__ g1, const float* __restrict__ b1,
    const float* __restrict__ m1, const float* __restrict__ var1,
    unsigned long long* __restrict__ s1m) // [8][128][32][32]
{
    int wid = (blockIdx.x * 256 + threadIdx.x) >> 6;   // 0..131071
    int lane = threadIdx.x & 63;                       // oc
    int b = wid >> 10;
    int pix = wid & 1023;
    int y = pix >> 5, x0 = pix & 31;

    float w[27];
#pragma unroll
    for (int j = 0; j < 27; ++j) w[j] = w1[lane * 27 + j];
    float scale = g1[lane] / sqrtf(var1[lane] + EPS);
    float bias  = b1[lane] - m1[lane] * scale;

    float v = 0.f;
    for (int t = 0; t < 8; ++t) {
        const float* xb = x + ((size_t)(t * 128 + b)) * 3072;
        float acc = 0.f;
#pragma unroll
        for (int ic = 0; ic < 3; ++ic)
#pragma unroll
        for (int dy = -1; dy <= 1; ++dy)
#pragma unroll
        for (int dx = -1; dx <= 1; ++dx) {
            int yy = y + dy, xx = x0 + dx;
            float xv = 0.f;
            if (yy >= 0 && yy < 32 && xx >= 0 && xx < 32)
                xv = xb[ic * 1024 + yy * 32 + xx];
            acc += xv * w[ic * 9 + (dy + 1) * 3 + (dx + 1)];
        }
        float pre = acc * scale + bias;
        v = v + (pre - v) * 0.5f;
        bool s = (v >= 1.0f);
        unsigned long long mask = __ballot(s);
        if (s) v = 0.f;
        if (lane == 0) s1m[((size_t)t * 128 + b) * 1024 + pix] = mask;
    }
}

// ---------------- conv2 + BN + LIF + pool + pack (one timestep) ----------------
// block: (b, 16x16 tile, 32-oc group). Input: bitmask tile in LDS.
__global__ __launch_bounds__(256) void conv2_lif_pool_pack(
    const unsigned long long* __restrict__ s1m,  // [128][32][32] (this t)
    const float* __restrict__ w2r,               // [576][128]
    const float* __restrict__ g, const float* __restrict__ bb,
    const float* __restrict__ mm, const float* __restrict__ vv,
    float* __restrict__ v2,                      // [128][128][32][32]
    unsigned int* __restrict__ s2pm)             // [128][16][16][4] (this t)
{
    __shared__ unsigned long long mt[18][18];
    __shared__ unsigned int sp[16][16];
    int b = blockIdx.x;
    int tile = blockIdx.y;          // 0..3
    int ocg = blockIdx.z;           // 0..3 -> 32 oc
    int ty0 = (tile >> 1) * 16, tx0 = (tile & 1) * 16;
    int tid = threadIdx.x;
    int py = tid >> 4, px = tid & 15;

    for (int i = tid; i < 324; i += 256) {
        int ly = i / 18, lx = i % 18;
        int yy = ty0 + ly - 1, xx = tx0 + lx - 1;
        unsigned long long mv = 0ULL;
        if (yy >= 0 && yy < 32 && xx >= 0 && xx < 32)
            mv = s1m[b * 1024 + yy * 32 + xx];
        mt[ly][lx] = mv;
    }
    __syncthreads();

    unsigned int sbits = 0;
#pragma unroll
    for (int c = 0; c < 2; ++c) {
        int oc0 = ocg * 32 + c * 16;
        float acc[16];
#pragma unroll
        for (int o = 0; o < 16; ++o) acc[o] = 0.f;
        for (int tap = 0; tap < 9; ++tap) {
            int dy = tap / 3, dx = tap % 3;
            unsigned long long m = mt[py + dy][px + dx];
            const float* wt = w2r + tap * 128 + oc0;
#pragma unroll
            for (int ic = 0; ic < 64; ++ic) {
                float f = (float)((m >> ic) & 1ULL);
                const float* wp = wt + ic * 1152;
#pragma unroll
                for (int o = 0; o < 16; ++o) acc[o] += f * wp[o];
            }
        }
        int yy = ty0 + py, xx = tx0 + px;
#pragma unroll
        for (int o = 0; o < 16; ++o) {
            int oc = oc0 + o;
            float scale = g[oc] / sqrtf(vv[oc] + EPS);
            float bias  = bb[oc] - mm[oc] * scale;
            float pre = acc[o] * scale + bias;
            size_t vi = (((size_t)b * 128 + oc) * 32 + yy) * 32 + xx;
            float v = v2[vi];
            v = v + (pre - v) * 0.5f;
            bool s = (v >= 1.0f);
            v2[vi] = s ? 0.f : v;
            sbits |= ((unsigned int)s) << (c * 16 + o);
        }
    }
    sp[py][px] = sbits;
    __syncthreads();
    if (tid < 64) {
        int py2 = tid >> 3, px2 = tid & 7;
        unsigned int mo = sp[2*py2][2*px2] | sp[2*py2][2*px2+1] |
                          sp[2*py2+1][2*px2] | sp[2*py2+1][2*px2+1];
        int gy = (ty0 >> 1) + py2, gx = (tx0 >> 1) + px2;
        s2pm[(b * 256 + gy * 16 + gx) * 4 + ocg] = mo;
    }
}

// ---------------- conv3 + BN + LIF + pool + store-as-float (one timestep) ----------------
__global__ __launch_bounds__(256) void conv3_lif_pool_store(
    const unsigned int* __restrict__ s2pm,   // [128][16][16][4] (this t)
    const float* __restrict__ w3r,           // [1152][256]
    const float* __restrict__ g, const float* __restrict__ bb,
    const float* __restrict__ mm, const float* __restrict__ vv,
    float* __restrict__ v3,                  // [128][256][16][16]
    float* __restrict__ s3f)                 // [128][16384] (this t)
{
    __shared__ unsigned long long mt[18][18][2];
    __shared__ unsigned int sp[16][16];
    int b = blockIdx.x;
    int ocg = blockIdx.y;           // 0..7 -> 32 oc
    int tid = threadIdx.x;
    int py = tid >> 4, px = tid & 15;

    const unsigned long long* s2m64 = (const unsigned long long*)s2pm;
    for (int i = tid; i < 324; i += 256) {
        int ly = i / 18, lx = i % 18;
        int yy = ly - 1, xx = lx - 1;
        unsigned long long m0 = 0ULL, m1 = 0ULL;
        if (yy >= 0 && yy < 16 && xx >= 0 && xx < 16) {
            size_t base = ((size_t)b * 256 + yy * 16 + xx) * 2;
            m0 = s2m64[base];
            m1 = s2m64[base + 1];
        }
        mt[ly][lx][0] = m0;
        mt[ly][lx][1] = m1;
    }
    __syncthreads();

    unsigned int sbits = 0;
#pragma unroll
    for (int c = 0; c < 2; ++c) {
        int oc0 = ocg * 32 + c * 16;
        float acc[16];
#pragma unroll
        for (int o = 0; o < 16; ++o) acc[o] = 0.f;
        for (int tap = 0; tap < 9; ++tap) {
            int dy = tap / 3, dx = tap % 3;
            unsigned long long m0 = mt[py + dy][px + dx][0];
            unsigned long long m1 = mt[py + dy][px + dx][1];
            const float* wt = w3r + tap * 256 + oc0;
#pragma unroll
            for (int ic = 0; ic < 64; ++ic) {
                float f = (float)((m0 >> ic) & 1ULL);
                const float* wp = wt + ic * 2304;
#pragma unroll
                for (int o = 0; o < 16; ++o) acc[o] += f * wp[o];
            }
#pragma unroll
            for (int ic = 0; ic < 64; ++ic) {
                float f = (float)((m1 >> ic) & 1ULL);
                const float* wp = wt + (ic + 64) * 2304;
#pragma unroll
                for (int o = 0; o < 16; ++o) acc[o] += f * wp[o];
            }
        }
#pragma unroll
        for (int o = 0; o < 16; ++o) {
            int oc = oc0 + o;
            float scale = g[oc] / sqrtf(vv[oc] + EPS);
            float bias  = bb[oc] - mm[oc] * scale;
            float pre = acc[o] * scale + bias;
            size_t vi = (((size_t)b * 256 + oc) * 16 + py) * 16 + px;
            float v = v3[vi];
            v = v + (pre - v) * 0.5f;
            bool s = (v >= 1.0f);
            v3[vi] = s ? 0.f : v;
            sbits |= ((unsigned int)s) << (c * 16 + o);
        }
    }
    sp[py][px] = sbits;
    __syncthreads();
    if (tid < 64) {
        int py2 = tid >> 3, px2 = tid & 7;
        unsigned int mo = sp[2*py2][2*px2] | sp[2*py2][2*px2+1] |
                          sp[2*py2+1][2*px2] | sp[2*py2+1][2*px2+1];
        // k index = oc*64 + py2*8 + px2
        float* dst = s3f + ((size_t)b * 256 + ocg * 32) * 64 + py2 * 8 + px2;
#pragma unroll
        for (int o = 0; o < 32; ++o)
            dst[(size_t)o * 64] = (float)((mo >> o) & 1u);
    }
}

// ---------------- FC GEMM: C[1024][512] = S[1024][16384] * W[512][16384]^T ----------------
__global__ __launch_bounds__(256) void fc_gemm(
    const float* __restrict__ S, const float* __restrict__ W,
    float* __restrict__ C)
{
    __shared__ float As[32][68];   // [k][m], stride 68 keeps float4 reads 16B-aligned
    __shared__ float Bs[32][36];   // [k][n]
    int m0 = blockIdx.x * 64;      // 16 blocks
    int n0 = blockIdx.y * 32;      // 16 blocks
    int tid = threadIdx.x;
    int tm = tid >> 4, tn = tid & 15;    // 16x16 compute grid; thread = 4m x 2n
    float acc[4][2] = {};

    for (int kc = 0; kc < 16384; kc += 32) {
        {
            int r = tid >> 2;              // 0..63
            int k8 = (tid & 3) * 8;        // 0,8,16,24
            const float* src = S + (size_t)(m0 + r) * 16384 + kc + k8;
            float4 a0 = ((const float4*)src)[0];
            float4 a1 = ((const float4*)src)[1];
            As[k8+0][r] = a0.x; As[k8+1][r] = a0.y; As[k8+2][r] = a0.z; As[k8+3][r] = a0.w;
            As[k8+4][r] = a1.x; As[k8+5][r] = a1.y; As[k8+6][r] = a1.z; As[k8+7][r] = a1.w;
        }
        {
            int r = tid >> 3;              // 0..31
            int k4 = (tid & 7) * 4;
            float4 bv = *(const float4*)(W + (size_t)(n0 + r) * 16384 + kc + k4);
            Bs[k4+0][r] = bv.x; Bs[k4+1][r] = bv.y; Bs[k4+2][r] = bv.z; Bs[k4+3][r] = bv.w;
        }
        __syncthreads();
#pragma unroll
        for (int kk = 0; kk < 32; ++kk) {
            float4 a = *(const float4*)&As[kk][tm * 4];
            float2 b2 = *(const float2*)&Bs[kk][tn * 2];
            acc[0][0] += a.x * b2.x; acc[0][1] += a.x * b2.y;
            acc[1][0] += a.y * b2.x; acc[1][1] += a.y * b2.y;
            acc[2][0] += a.z * b2.x; acc[2][1] += a.z * b2.y;
            acc[3][0] += a.w * b2.x; acc[3][1] += a.w * b2.y;
        }
        __syncthreads();
    }
#pragma unroll
    for (int i = 0; i < 4; ++i) {
        float2 o2 = make_float2(acc[i][0], acc[i][1]);
        *(float2*)&C[(size_t)(m0 + tm * 4 + i) * 512 + n0 + tn * 2] = o2;
    }
}

// ---------------- LIF over FC output + temporal mean ----------------
__global__ void lif4_mean(const float* __restrict__ C, float* __restrict__ feat) {
    int i = blockIdx.x * 256 + threadIdx.x;   // 65536 = [b][f]
    if (i >= 65536) return;
    int b = i >> 9, f = i & 511;
    float v = 0.f, sum = 0.f;
#pragma unroll
    for (int t = 0; t < 8; ++t) {
        float pre = C[((size_t)t * 128 + b) * 512 + f];
        v = v + (pre - v) * 0.5f;
        if (v >= 1.0f) { sum += 1.f; v = 0.f; }
    }
    feat[i] = sum * 0.125f;
}

// ---------------- prototype normalization ----------------
__global__ void protos_norm(const float* __restrict__ P, float* __restrict__ pn) {
    int p = blockIdx.x;
    int lane = threadIdx.x;   // 64
    float ss = 0.f;
    for (int f = lane; f < 512; f += 64) { float x = P[p * 512 + f]; ss += x * x; }
#pragma unroll
    for (int o = 32; o > 0; o >>= 1) ss += __shfl_xor(ss, o);
    float inv = 1.f / fmaxf(sqrtf(ss), 1e-12f);
    for (int f = lane; f < 512; f += 64) pn[p * 512 + f] = P[p * 512 + f] * inv;
}

// ---------------- final logits ----------------
__global__ void final_logits(const float* __restrict__ feat, const float* __restrict__ pn,
                             float* __restrict__ out) {
    int b = blockIdx.x;
    int lane = threadIdx.x;   // 64
    float fr[8];
    float ss = 0.f;
#pragma unroll
    for (int j = 0; j < 8; ++j) { fr[j] = feat[b * 512 + j * 64 + lane]; ss += fr[j] * fr[j]; }
#pragma unroll
    for (int o = 32; o > 0; o >>= 1) ss += __shfl_xor(ss, o);
    float inv = 10.f / fmaxf(sqrtf(ss), 1e-12f);
    for (int p = 0; p < 10; ++p) {
        float d = 0.f;
#pragma unroll
        for (int j = 0; j < 8; ++j) d += fr[j] * pn[p * 512 + j * 64 + lane];
#pragma unroll
        for (int o = 32; o > 0; o >>= 1) d += __shfl_xor(d, o);
        if (lane == 0) out[b * 10 + p] = d * inv;
    }
}

extern "C" void kernel_launch(void* const* d_in, const int* in_sizes, int n_in,
                              void* d_out, int out_size, void* d_ws, size_t ws_size,
                              hipStream_t stream) {
    const float* x      = (const float*)d_in[0];
    const float* w1     = (const float*)d_in[1];
    const float* w2     = (const float*)d_in[2];
    const float* w3     = (const float*)d_in[3];
    const float* fc1    = (const float*)d_in[4];
    const float* protos = (const float*)d_in[5];
    const float* g1 = (const float*)d_in[6],  *b1 = (const float*)d_in[7];
    const float* m1 = (const float*)d_in[8],  *v1 = (const float*)d_in[9];
    const float* g2 = (const float*)d_in[10], *b2 = (const float*)d_in[11];
    const float* m2 = (const float*)d_in[12], *v2p = (const float*)d_in[13];
    const float* g3 = (const float*)d_in[14], *b3 = (const float*)d_in[15];
    const float* m3 = (const float*)d_in[16], *v3p = (const float*)d_in[17];

    char* ws = (char*)d_ws;
    float* w2r  = (float*)(ws + OFF_W2R);
    float* w3r  = (float*)(ws + OFF_W3R);
    unsigned long long* s1m = (unsigned long long*)(ws + OFF_S1M);
    unsigned int* s2pm = (unsigned int*)(ws + OFF_S2PM);
    float* v2   = (float*)(ws + OFF_V2);
    float* v3   = (float*)(ws + OFF_V3);
    float* s3f  = (float*)(ws + OFF_S3F);
    float* pre4 = (float*)(ws + OFF_PRE4);
    float* feat = (float*)(ws + OFF_FEAT);
    float* pn   = (float*)(ws + OFF_PN);

    hipMemsetAsync(v2, 0, 67108864ULL, stream);
    hipMemsetAsync(v3, 0, 33554432ULL, stream);
    repack_w2<<<(73728 + 255) / 256, 256, 0, stream>>>(w2, w2r);
    repack_w3<<<(294912 + 255) / 256, 256, 0, stream>>>(w3, w3r);

    conv1_lif_pack<<<32768, 256, 0, stream>>>(x, w1, g1, b1, m1, v1, s1m);

    for (int t = 0; t < 8; ++t) {
        conv2_lif_pool_pack<<<dim3(128, 4, 4), 256, 0, stream>>>(
            s1m + (size_t)t * 131072, w2r, g2, b2, m2, v2p, v2,
            s2pm + (size_t)t * 131072);
        conv3_lif_pool_store<<<dim3(128, 8), 256, 0, stream>>>(
            s2pm + (size_t)t * 131072, w3r, g3, b3, m3, v3p, v3,
            s3f + (size_t)t * 128 * 16384);
    }

    fc_gemm<<<dim3(16, 16), 256, 0, stream>>>(s3f, fc1, pre4);
    lif4_mean<<<256, 256, 0, stream>>>(pre4, feat);
    protos_norm<<<10, 64, 0, stream>>>(protos, pn);
    final_logits<<<128, 64, 0, stream>>>(feat, pn, (float*)d_out);
}

// Round 2
// 1349.823 us; speedup vs baseline: 5.5981x; 5.5981x over previous
//
#include <hip/hip_runtime.h>
#include <stdint.h>

#define EPS 1e-5f

typedef __attribute__((ext_vector_type(4))) float f32x4;
typedef __attribute__((ext_vector_type(8))) __bf16 bf16x8;

__device__ __forceinline__ void gl_lds16(const void* g, void* l) {
    __builtin_amdgcn_global_load_lds(
        (const __attribute__((address_space(1))) void*)g,
        (__attribute__((address_space(3))) void*)l, 16, 0, 0);
}

__device__ __forceinline__ unsigned short f2bf(float f) {
    unsigned u = __builtin_bit_cast(unsigned, f);
    unsigned r = (u + 0x7FFFu + ((u >> 16) & 1u)) >> 16;   // RNE
    return (unsigned short)r;
}
__device__ __forceinline__ float bf2f(unsigned short h) {
    unsigned u = ((unsigned)h) << 16;
    return __builtin_bit_cast(float, u);
}

// ---------------- workspace layout (bytes) ----------------
#define OFF_W2S   0ULL                         // [3][9][128][64] bf16   = 442368
#define OFF_W3S   442368ULL                    // [3][18][256][64] bf16  = 1769472
#define OFF_FCS   2211840ULL                   // [3][256][512][64] bf16 = 50331648
#define OFF_S1M   52543488ULL                  // [8][128][1024] u64     = 8388608
#define OFF_S2PM  60932096ULL                  // [128][256][2] u64      = 524288
#define OFF_V2    61456384ULL                  // [128][1024][128] f32   = 67108864
#define OFF_V3    128565248ULL                 // [128][256][256] f32    = 33554432
#define OFF_S3    162119680ULL                 // [8][128][16384] bf16   = 33554432
#define OFF_PRE4P 195674112ULL                 // [8][1024][512] f32     = 16777216
#define OFF_FEAT  212451328ULL                 // [128][512] f32         = 262144
#define OFF_PN    212713472ULL                 // [10][512] f32          = 20480

// ---------------- weight repack + 3-way bf16 split (hi/mid/lo) ----------------
// w2: [128][64][3][3] -> w2s[split][tap][oc][ic], 16B chunks XOR-swizzled by (oc&7)
__global__ void repack_w2s(const float* __restrict__ w2, unsigned short* __restrict__ out) {
    int i = blockIdx.x * 256 + threadIdx.x;   // 73728
    if (i >= 73728) return;
    int oc = i / 576, rem = i % 576;
    int ic = rem / 9, tap = rem % 9;
    float w = w2[i];
    unsigned short hi = f2bf(w);  float r1 = w - bf2f(hi);
    unsigned short md = f2bf(r1); float r2 = r1 - bf2f(md);
    unsigned short lo = f2bf(r2);
    size_t base = ((size_t)(tap * 128 + oc)) * 64 + (((ic >> 3) ^ (oc & 7)) << 3) + (ic & 7);
    out[base] = hi; out[base + 73728] = md; out[base + 147456] = lo;
}
// w3: [256][128][3][3] -> w3s[split][cc=tap*2+h][oc][icl]
__global__ void repack_w3s(const float* __restrict__ w3, unsigned short* __restrict__ out) {
    int i = blockIdx.x * 256 + threadIdx.x;   // 294912
    if (i >= 294912) return;
    int oc = i / 1152, rem = i % 1152;
    int ic = rem / 9, tap = rem % 9;
    float w = w3[i];
    unsigned short hi = f2bf(w);  float r1 = w - bf2f(hi);
    unsigned short md = f2bf(r1); float r2 = r1 - bf2f(md);
    unsigned short lo = f2bf(r2);
    int cc = tap * 2 + (ic >> 6), icl = ic & 63;
    size_t base = ((size_t)(cc * 256 + oc)) * 64 + (((icl >> 3) ^ (oc & 7)) << 3) + (icl & 7);
    out[base] = hi; out[base + 294912] = md; out[base + 589824] = lo;
}
// fc1_w: [512][16384] -> fcs[split][cc=d>>6][f][kl]
__global__ void repack_fcs(const float* __restrict__ fw, unsigned short* __restrict__ out) {
    int i = blockIdx.x * 256 + threadIdx.x;   // 8388608
    if (i >= 8388608) return;
    int f = i >> 14, d = i & 16383;
    float w = fw[i];
    unsigned short hi = f2bf(w);  float r1 = w - bf2f(hi);
    unsigned short md = f2bf(r1); float r2 = r1 - bf2f(md);
    unsigned short lo = f2bf(r2);
    int cc = d >> 6, kl = d & 63;
    size_t base = (((size_t)cc << 9) + f) * 64 + (((kl >> 3) ^ (f & 7)) << 3) + (kl & 7);
    out[base] = hi; out[base + 8388608] = md; out[base + 16777216] = lo;
}

// ---------------- conv1 + BN + LIF, spikes bit-packed via ballot ----------------
__global__ __launch_bounds__(256) void conv1_lif_pack(
    const float* __restrict__ x, const float* __restrict__ w1,
    const float* __restrict__ g1, const float* __restrict__ b1,
    const float* __restrict__ m1, const float* __restrict__ var1,
    unsigned long long* __restrict__ s1m)
{
    int wid = (blockIdx.x * 256 + threadIdx.x) >> 6;
    int lane = threadIdx.x & 63;
    int b = wid >> 10;
    int pix = wid & 1023;
    int y = pix >> 5, x0 = pix & 31;

    float w[27];
#pragma unroll
    for (int j = 0; j < 27; ++j) w[j] = w1[lane * 27 + j];
    float scale = g1[lane] / sqrtf(var1[lane] + EPS);
    float bias  = b1[lane] - m1[lane] * scale;

    float v = 0.f;
    for (int t = 0; t < 8; ++t) {
        const float* xb = x + ((size_t)(t * 128 + b)) * 3072;
        float acc = 0.f;
#pragma unroll
        for (int ic = 0; ic < 3; ++ic)
#pragma unroll
        for (int dy = -1; dy <= 1; ++dy)
#pragma unroll
        for (int dx = -1; dx <= 1; ++dx) {
            int yy = y + dy, xx = x0 + dx;
            float xv = 0.f;
            if (yy >= 0 && yy < 32 && xx >= 0 && xx < 32)
                xv = xb[ic * 1024 + yy * 32 + xx];
            acc += xv * w[ic * 9 + (dy + 1) * 3 + (dx + 1)];
        }
        float pre = acc * scale + bias;
        v = v + (pre - v) * 0.5f;
        bool s = (v >= 1.0f);
        unsigned long long mask = __ballot(s);
        if (s) v = 0.f;
        if (lane == 0) s1m[((size_t)t * 128 + b) * 1024 + pix] = mask;
    }
}

// ---------------- conv2 MFMA GEMM + BN + LIF + pool + bitpack (one t) ----------------
// 128x128 tile; M = b*1024 + pix (4 image rows/block); N = 128 oc; K = 9 taps x 64 ic x 3 splits
__global__ __launch_bounds__(256, 2) void conv2_mfma(
    const unsigned long long* __restrict__ s1m,   // [128][1024] this t
    const unsigned short* __restrict__ w2s,
    const float* __restrict__ g, const float* __restrict__ bb,
    const float* __restrict__ mm, const float* __restrict__ vv,
    float* __restrict__ v2,                       // [128][1024][128]
    unsigned long long* __restrict__ s2pm)        // [128][256][2]
{
    __shared__ unsigned short A[128 * 64];        // 16KB, [m][k] swizzled
    __shared__ unsigned short B[3 * 128 * 64];    // 48KB, [n][k] swizzled (pre-swizzled in global)
    __shared__ unsigned long long mt[6][34];
    __shared__ unsigned short pm16[2][16][8];

    int tid = threadIdx.x;
    int m0 = blockIdx.x << 7;
    int b = m0 >> 10;
    int pix0 = m0 & 1023;
    int y0 = pix0 >> 5;

    for (int i = tid; i < 204; i += 256) {
        int ly = i / 34, lx = i % 34;
        int yy = y0 + ly - 1, xx = lx - 1;
        unsigned long long mv = 0ULL;
        if (yy >= 0 && yy < 32 && xx >= 0 && xx < 32)
            mv = s1m[(b << 10) + (yy << 5) + xx];
        mt[ly][lx] = mv;
    }

    int w = tid >> 6, lane = tid & 63;
    int wm = w & 1, wn = w >> 1;
    int q = lane >> 4, r = lane & 15;
    int swr = r & 7;
    int am = tid >> 1, ah = tid & 1;
    int ay = am >> 5, ax = am & 31;
    int asw = am & 7;

    f32x4 acc[4][4];
#pragma unroll
    for (int i = 0; i < 4; ++i)
#pragma unroll
        for (int j = 0; j < 4; ++j) acc[i][j] = (f32x4){0.f, 0.f, 0.f, 0.f};

    const char* w2sb = (const char*)w2s;

    for (int tap = 0; tap < 9; ++tap) {
        int dy = tap / 3, dx = tap - dy * 3;
        __syncthreads();
        {   // build A-tile from bitmask
            unsigned long long mk = mt[ay + dy][ax + dx];
            unsigned int wbits = (unsigned int)(mk >> (ah << 5));
#pragma unroll
            for (int c4 = 0; c4 < 4; ++c4) {
                unsigned int bt = wbits >> (c4 << 3);
                uint4 val;
                val.x = ((bt & 1u) ? 0x3F80u : 0u)  | ((bt & 2u) ? 0x3F800000u : 0u);
                val.y = ((bt & 4u) ? 0x3F80u : 0u)  | ((bt & 8u) ? 0x3F800000u : 0u);
                val.z = ((bt & 16u) ? 0x3F80u : 0u) | ((bt & 32u) ? 0x3F800000u : 0u);
                val.w = ((bt & 64u) ? 0x3F80u : 0u) | ((bt & 128u) ? 0x3F800000u : 0u);
                int c = (ah << 2) + c4;
                *(uint4*)((char*)A + am * 128 + ((c ^ asw) << 4)) = val;
            }
        }
        {   // stage B: 3 splits x 16KB, direct-to-LDS
            const char* gb = w2sb + tap * 16384 + (w << 12) + (lane << 4);
            char* lb = (char*)B + (w << 12);
#pragma unroll
            for (int s = 0; s < 3; ++s)
#pragma unroll
                for (int p = 0; p < 4; ++p)
                    gl_lds16(gb + s * 147456 + (p << 10), lb + s * 16384 + (p << 10));
        }
        __syncthreads();
#pragma unroll
        for (int ks = 0; ks < 2; ++ks) {
            bf16x8 af[4];
#pragma unroll
            for (int i = 0; i < 4; ++i)
                af[i] = *(const bf16x8*)((const char*)A + (wm * 64 + i * 16 + r) * 128 + ((((ks << 2) + q) ^ swr) << 4));
#pragma unroll
            for (int s = 0; s < 3; ++s) {
                bf16x8 bfr[4];
#pragma unroll
                for (int j = 0; j < 4; ++j)
                    bfr[j] = *(const bf16x8*)((const char*)B + s * 16384 + (wn * 64 + j * 16 + r) * 128 + ((((ks << 2) + q) ^ swr) << 4));
#pragma unroll
                for (int i = 0; i < 4; ++i)
#pragma unroll
                    for (int j = 0; j < 4; ++j)
                        acc[i][j] = __builtin_amdgcn_mfma_f32_16x16x32_bf16(af[i], bfr[j], acc[i][j], 0, 0, 0);
            }
        }
    }

    // epilogue: BN + LIF (C layout: col = wn*64+j*16+r, row m = wm*64+i*16+q*4+reg)
    float scl[4], bia[4];
#pragma unroll
    for (int j = 0; j < 4; ++j) {
        int oc = wn * 64 + j * 16 + r;
        float s0 = g[oc] / sqrtf(vv[oc] + EPS);
        scl[j] = s0;
        bia[j] = bb[oc] - mm[oc] * s0;
    }
    unsigned long long S = 0ULL;
#pragma unroll
    for (int i = 0; i < 4; ++i) {
        int pixr = pix0 + wm * 64 + i * 16 + (q << 2);
#pragma unroll
        for (int j = 0; j < 4; ++j) {
            size_t vb = ((size_t)(b << 10) + pixr) * 128 + wn * 64 + j * 16 + r;
#pragma unroll
            for (int reg = 0; reg < 4; ++reg) {
                float pre = acc[i][j][reg] * scl[j] + bia[j];
                float v = v2[vb + (size_t)reg * 128];
                v = v + (pre - v) * 0.5f;
                bool sp = (v >= 1.0f);
                v2[vb + (size_t)reg * 128] = sp ? 0.f : v;
                if (sp) S |= 1ULL << (i * 16 + j * 4 + reg);
            }
        }
    }
    // 2x2 pool (in-lane: x-pairs=reg pairs, x-half=i&1, y=i>>1) + bitpack via ballot
#pragma unroll
    for (int b1 = 0; b1 < 2; ++b1)
#pragma unroll
        for (int u = 0; u < 2; ++u)
#pragma unroll
            for (int j = 0; j < 4; ++j) {
                int k0 = b1 * 16 + j * 4 + 2 * u;
                bool sp = (((S >> k0) | (S >> (k0 + 1)) | (S >> (k0 + 32)) | (S >> (k0 + 33))) & 1ULL) != 0;
                unsigned long long mk = __ballot(sp);
                if (r == 0)
                    pm16[wm][b1 * 8 + (q << 1) + u][wn * 4 + j] = (unsigned short)(mk >> (q << 4));
            }
    __syncthreads();
    if (tid < 64) {
        int py = tid >> 5, px = (tid >> 1) & 15, h = tid & 1;
        unsigned long long v = *(unsigned long long*)&pm16[py][px][h << 2];
        s2pm[((size_t)(b << 8) + ((y0 >> 1) + py) * 16 + px) * 2 + h] = v;
    }
}

// ---------------- conv3 MFMA GEMM + BN + LIF + pool -> bf16 spikes (one t) ----------------
// M = b*256 + pix (8 image rows/block); N-tile = 128 of 256; K = 18 chunks x 64 x 3 splits
__global__ __launch_bounds__(256, 2) void conv3_mfma(
    const unsigned long long* __restrict__ s2pm,  // [128][256][2]
    const unsigned short* __restrict__ w3s,
    const float* __restrict__ g, const float* __restrict__ bb,
    const float* __restrict__ mm, const float* __restrict__ vv,
    float* __restrict__ v3,                       // [128][256][256]
    unsigned short* __restrict__ s3t)             // [128][16384] bf16, this t, swizzled
{
    __shared__ unsigned short A[128 * 64];
    __shared__ unsigned short B[3 * 128 * 64];
    __shared__ unsigned long long mt3[10][18][2];

    int tid = threadIdx.x;
    int m0 = blockIdx.x << 7;
    int n0 = blockIdx.y << 7;
    int b = m0 >> 8;
    int pix0 = m0 & 255;
    int y0 = pix0 >> 4;     // 0 or 8

    for (int i = tid; i < 180; i += 256) {
        int ly = i / 18, lx = i % 18;
        int yy = y0 + ly - 1, xx = lx - 1;
        unsigned long long v0 = 0ULL, v1 = 0ULL;
        if (yy >= 0 && yy < 16 && xx >= 0 && xx < 16) {
            const unsigned long long* p = &s2pm[((size_t)(b << 8) + (yy << 4) + xx) * 2];
            v0 = p[0]; v1 = p[1];
        }
        mt3[ly][lx][0] = v0; mt3[ly][lx][1] = v1;
    }

    int w = tid >> 6, lane = tid & 63;
    int wm = w & 1, wn = w >> 1;
    int q = lane >> 4, r = lane & 15;
    int swr = r & 7;
    int am = tid >> 1, ah = tid & 1;
    int ay = am >> 4, ax = am & 15;
    int asw = am & 7;

    f32x4 acc[4][4];
#pragma unroll
    for (int i = 0; i < 4; ++i)
#pragma unroll
        for (int j = 0; j < 4; ++j) acc[i][j] = (f32x4){0.f, 0.f, 0.f, 0.f};

    const char* w3sb = (const char*)w3s;

    for (int cc = 0; cc < 18; ++cc) {
        int tap = cc >> 1, h = cc & 1;
        int dy = tap / 3, dx = tap - dy * 3;
        __syncthreads();
        {
            unsigned long long mk = mt3[ay + dy][ax + dx][h];
            unsigned int wbits = (unsigned int)(mk >> (ah << 5));
#pragma unroll
            for (int c4 = 0; c4 < 4; ++c4) {
                unsigned int bt = wbits >> (c4 << 3);
                uint4 val;
                val.x = ((bt & 1u) ? 0x3F80u : 0u)  | ((bt & 2u) ? 0x3F800000u : 0u);
                val.y = ((bt & 4u) ? 0x3F80u : 0u)  | ((bt & 8u) ? 0x3F800000u : 0u);
                val.z = ((bt & 16u) ? 0x3F80u : 0u) | ((bt & 32u) ? 0x3F800000u : 0u);
                val.w = ((bt & 64u) ? 0x3F80u : 0u) | ((bt & 128u) ? 0x3F800000u : 0u);
                int c = (ah << 2) + c4;
                *(uint4*)((char*)A + am * 128 + ((c ^ asw) << 4)) = val;
            }
        }
        {
            const char* gb = w3sb + cc * 32768 + n0 * 128 + (w << 12) + (lane << 4);
            char* lb = (char*)B + (w << 12);
#pragma unroll
            for (int s = 0; s < 3; ++s)
#pragma unroll
                for (int p = 0; p < 4; ++p)
                    gl_lds16(gb + s * 589824 + (p << 10), lb + s * 16384 + (p << 10));
        }
        __syncthreads();
#pragma unroll
        for (int ks = 0; ks < 2; ++ks) {
            bf16x8 af[4];
#pragma unroll
            for (int i = 0; i < 4; ++i)
                af[i] = *(const bf16x8*)((const char*)A + (wm * 64 + i * 16 + r) * 128 + ((((ks << 2) + q) ^ swr) << 4));
#pragma unroll
            for (int s = 0; s < 3; ++s) {
                bf16x8 bfr[4];
#pragma unroll
                for (int j = 0; j < 4; ++j)
                    bfr[j] = *(const bf16x8*)((const char*)B + s * 16384 + (wn * 64 + j * 16 + r) * 128 + ((((ks << 2) + q) ^ swr) << 4));
#pragma unroll
                for (int i = 0; i < 4; ++i)
#pragma unroll
                    for (int j = 0; j < 4; ++j)
                        acc[i][j] = __builtin_amdgcn_mfma_f32_16x16x32_bf16(af[i], bfr[j], acc[i][j], 0, 0, 0);
            }
        }
    }

    float scl[4], bia[4];
#pragma unroll
    for (int j = 0; j < 4; ++j) {
        int oc = n0 + wn * 64 + j * 16 + r;
        float s0 = g[oc] / sqrtf(vv[oc] + EPS);
        scl[j] = s0;
        bia[j] = bb[oc] - mm[oc] * s0;
    }
    unsigned long long S = 0ULL;
#pragma unroll
    for (int i = 0; i < 4; ++i) {
        int pixr = pix0 + wm * 64 + i * 16 + (q << 2);
#pragma unroll
        for (int j = 0; j < 4; ++j) {
            size_t vb = ((size_t)(b << 8) + pixr) * 256 + n0 + wn * 64 + j * 16 + r;
#pragma unroll
            for (int reg = 0; reg < 4; ++reg) {
                float pre = acc[i][j][reg] * scl[j] + bia[j];
                float v = v3[vb + (size_t)reg * 256];
                v = v + (pre - v) * 0.5f;
                bool sp = (v >= 1.0f);
                v3[vb + (size_t)reg * 256] = sp ? 0.f : v;
                if (sp) S |= 1ULL << (i * 16 + j * 4 + reg);
            }
        }
    }
    // pool (x-pairs = reg pairs; y-pairs = frag i pairs) -> bf16 spike, swizzled by (b&7)
    int bsw = b & 7;
#pragma unroll
    for (int a2 = 0; a2 < 2; ++a2)
#pragma unroll
        for (int u = 0; u < 2; ++u)
#pragma unroll
            for (int j = 0; j < 4; ++j) {
                int kA = 32 * a2 + j * 4 + 2 * u;
                bool sp = (((S >> kA) | (S >> (kA + 1)) | (S >> (kA + 16)) | (S >> (kA + 17))) & 1ULL) != 0;
                int oc = n0 + wn * 64 + j * 16 + r;
                int y2 = (y0 >> 1) + wm * 2 + a2;
                int x2 = (q << 1) + u;
                s3t[(size_t)(b << 14) + oc * 64 + ((y2 ^ bsw) << 3) + x2] =
                    (unsigned short)(sp ? 0x3F80 : 0);
            }
}

// ---------------- FC MFMA GEMM, split-K into 8 deterministic partials ----------------
__global__ __launch_bounds__(256, 2) void fc_mfma(
    const unsigned short* __restrict__ s3,    // [1024][16384] bf16, swizzled by (m&7)
    const unsigned short* __restrict__ fcs,
    float* __restrict__ pre4p)                // [8][1024][512]
{
    __shared__ unsigned short A[128 * 64];
    __shared__ unsigned short B[3 * 128 * 64];

    int tid = threadIdx.x;
    int m0 = blockIdx.x << 7;
    int n0 = blockIdx.y << 7;
    int kseg = blockIdx.z;
    int cc0 = kseg << 5;

    int w = tid >> 6, lane = tid & 63;
    int wm = w & 1, wn = w >> 1;
    int q = lane >> 4, r = lane & 15;
    int swr = r & 7;

    f32x4 acc[4][4];
#pragma unroll
    for (int i = 0; i < 4; ++i)
#pragma unroll
        for (int j = 0; j < 4; ++j) acc[i][j] = (f32x4){0.f, 0.f, 0.f, 0.f};

    const char* s3b = (const char*)s3;
    const char* fcsb = (const char*)fcs;

    for (int cc = cc0; cc < cc0 + 32; ++cc) {
        __syncthreads();
        {   // stage A from s3 (per-lane global addresses, contiguous LDS)
            char* lb = (char*)A + (w << 12);
#pragma unroll
            for (int p = 0; p < 4; ++p)
                gl_lds16(s3b + (size_t)(m0 + w * 32 + p * 8 + (lane >> 3)) * 32768
                             + cc * 128 + ((lane & 7) << 4),
                         lb + (p << 10));
        }
        {
            const char* gb = fcsb + cc * 65536 + n0 * 128 + (w << 12) + (lane << 4);
            char* lb = (char*)B + (w << 12);
#pragma unroll
            for (int s = 0; s < 3; ++s)
#pragma unroll
                for (int p = 0; p < 4; ++p)
                    gl_lds16(gb + s * 16777216 + (p << 10), lb + s * 16384 + (p << 10));
        }
        __syncthreads();
#pragma unroll
        for (int ks = 0; ks < 2; ++ks) {
            bf16x8 af[4];
#pragma unroll
            for (int i = 0; i < 4; ++i)
                af[i] = *(const bf16x8*)((const char*)A + (wm * 64 + i * 16 + r) * 128 + ((((ks << 2) + q) ^ swr) << 4));
#pragma unroll
            for (int s = 0; s < 3; ++s) {
                bf16x8 bfr[4];
#pragma unroll
                for (int j = 0; j < 4; ++j)
                    bfr[j] = *(const bf16x8*)((const char*)B + s * 16384 + (wn * 64 + j * 16 + r) * 128 + ((((ks << 2) + q) ^ swr) << 4));
#pragma unroll
                for (int i = 0; i < 4; ++i)
#pragma unroll
                    for (int j = 0; j < 4; ++j)
                        acc[i][j] = __builtin_amdgcn_mfma_f32_16x16x32_bf16(af[i], bfr[j], acc[i][j], 0, 0, 0);
            }
        }
    }
#pragma unroll
    for (int i = 0; i < 4; ++i) {
#pragma unroll
        for (int j = 0; j < 4; ++j) {
            size_t base = ((size_t)kseg * 1024 + m0 + wm * 64 + i * 16 + (q << 2)) * 512
                        + n0 + wn * 64 + j * 16 + r;
#pragma unroll
            for (int reg = 0; reg < 4; ++reg)
                pre4p[base + (size_t)reg * 512] = acc[i][j][reg];
        }
    }
}

// ---------------- LIF over FC output (sum 8 partials deterministically) + mean ----------------
__global__ void lif4_mean(const float* __restrict__ P, float* __restrict__ feat) {
    int i = blockIdx.x * 256 + threadIdx.x;
    if (i >= 65536) return;
    int b = i >> 9, f = i & 511;
    float v = 0.f, sum = 0.f;
#pragma unroll
    for (int t = 0; t < 8; ++t) {
        float pre = 0.f;
#pragma unroll
        for (int s = 0; s < 8; ++s)
            pre += P[(size_t)s * 524288 + (size_t)(t * 128 + b) * 512 + f];
        v = v + (pre - v) * 0.5f;
        if (v >= 1.0f) { sum += 1.f; v = 0.f; }
    }
    feat[i] = sum * 0.125f;
}

__global__ void protos_norm(const float* __restrict__ P, float* __restrict__ pn) {
    int p = blockIdx.x;
    int lane = threadIdx.x;
    float ss = 0.f;
    for (int f = lane; f < 512; f += 64) { float x = P[p * 512 + f]; ss += x * x; }
#pragma unroll
    for (int o = 32; o > 0; o >>= 1) ss += __shfl_xor(ss, o);
    float inv = 1.f / fmaxf(sqrtf(ss), 1e-12f);
    for (int f = lane; f < 512; f += 64) pn[p * 512 + f] = P[p * 512 + f] * inv;
}

__global__ void final_logits(const float* __restrict__ feat, const float* __restrict__ pn,
                             float* __restrict__ out) {
    int b = blockIdx.x;
    int lane = threadIdx.x;
    float fr[8];
    float ss = 0.f;
#pragma unroll
    for (int j = 0; j < 8; ++j) { fr[j] = feat[b * 512 + j * 64 + lane]; ss += fr[j] * fr[j]; }
#pragma unroll
    for (int o = 32; o > 0; o >>= 1) ss += __shfl_xor(ss, o);
    float inv = 10.f / fmaxf(sqrtf(ss), 1e-12f);
    for (int p = 0; p < 10; ++p) {
        float d = 0.f;
#pragma unroll
        for (int j = 0; j < 8; ++j) d += fr[j] * pn[p * 512 + j * 64 + lane];
#pragma unroll
        for (int o = 32; o > 0; o >>= 1) d += __shfl_xor(d, o);
        if (lane == 0) out[b * 10 + p] = d * inv;
    }
}

extern "C" void kernel_launch(void* const* d_in, const int* in_sizes, int n_in,
                              void* d_out, int out_size, void* d_ws, size_t ws_size,
                              hipStream_t stream) {
    const float* x      = (const float*)d_in[0];
    const float* w1     = (const float*)d_in[1];
    const float* w2     = (const float*)d_in[2];
    const float* w3     = (const float*)d_in[3];
    const float* fc1    = (const float*)d_in[4];
    const float* protos = (const float*)d_in[5];
    const float* g1 = (const float*)d_in[6],  *b1 = (const float*)d_in[7];
    const float* m1 = (const float*)d_in[8],  *v1 = (const float*)d_in[9];
    const float* g2 = (const float*)d_in[10], *b2 = (const float*)d_in[11];
    const float* m2 = (const float*)d_in[12], *v2p = (const float*)d_in[13];
    const float* g3 = (const float*)d_in[14], *b3 = (const float*)d_in[15];
    const float* m3 = (const float*)d_in[16], *v3p = (const float*)d_in[17];

    char* ws = (char*)d_ws;
    unsigned short* w2s = (unsigned short*)(ws + OFF_W2S);
    unsigned short* w3s = (unsigned short*)(ws + OFF_W3S);
    unsigned short* fcs = (unsigned short*)(ws + OFF_FCS);
    unsigned long long* s1m  = (unsigned long long*)(ws + OFF_S1M);
    unsigned long long* s2pm = (unsigned long long*)(ws + OFF_S2PM);
    float* v2    = (float*)(ws + OFF_V2);
    float* v3    = (float*)(ws + OFF_V3);
    unsigned short* s3 = (unsigned short*)(ws + OFF_S3);
    float* pre4p = (float*)(ws + OFF_PRE4P);
    float* feat  = (float*)(ws + OFF_FEAT);
    float* pn    = (float*)(ws + OFF_PN);

    hipMemsetAsync(v2, 0, 67108864ULL, stream);
    hipMemsetAsync(v3, 0, 33554432ULL, stream);
    repack_w2s<<<288, 256, 0, stream>>>(w2, w2s);
    repack_w3s<<<1152, 256, 0, stream>>>(w3, w3s);
    repack_fcs<<<32768, 256, 0, stream>>>(fc1, fcs);

    conv1_lif_pack<<<32768, 256, 0, stream>>>(x, w1, g1, b1, m1, v1, s1m);

    for (int t = 0; t < 8; ++t) {
        conv2_mfma<<<1024, 256, 0, stream>>>(
            s1m + (size_t)t * 131072, w2s, g2, b2, m2, v2p, v2, s2pm);
        conv3_mfma<<<dim3(256, 2), 256, 0, stream>>>(
            s2pm, w3s, g3, b3, m3, v3p, v3, s3 + (size_t)t * 2097152);
    }

    fc_mfma<<<dim3(8, 4, 8), 256, 0, stream>>>(s3, fcs, pre4p);
    lif4_mean<<<256, 256, 0, stream>>>(pre4p, feat);
    protos_norm<<<10, 64, 0, stream>>>(protos, pn);
    final_logits<<<128, 64, 0, stream>>>(feat, pn, (float*)d_out);
}

// Round 3
// 1033.389 us; speedup vs baseline: 7.3124x; 1.3062x over previous
//
#include <hip/hip_runtime.h>
#include <stdint.h>

#define EPS 1e-5f

typedef __attribute__((ext_vector_type(4))) float f32x4;
typedef __attribute__((ext_vector_type(8))) __bf16 bf16x8;

__device__ __forceinline__ void gl_lds16(const void* g, void* l) {
    __builtin_amdgcn_global_load_lds(
        (const __attribute__((address_space(1))) void*)g,
        (__attribute__((address_space(3))) void*)l, 16, 0, 0);
}

__device__ __forceinline__ unsigned short f2bf(float f) {
    unsigned u = __builtin_bit_cast(unsigned, f);
    unsigned r = (u + 0x7FFFu + ((u >> 16) & 1u)) >> 16;   // RNE
    return (unsigned short)r;
}
__device__ __forceinline__ float bf2f(unsigned short h) {
    unsigned u = ((unsigned)h) << 16;
    return __builtin_bit_cast(float, u);
}

// ---------------- workspace layout (bytes) ----------------
#define OFF_W2S   0ULL                         // [3][9][128][64] bf16   = 442368
#define OFF_W3S   442368ULL                    // [3][18][256][64] bf16  = 1769472
#define OFF_FCS   2211840ULL                   // [3][256][512][64] bf16 = 50331648
#define OFF_S1M   52543488ULL                  // [8][128][1024] u64     = 8388608
#define OFF_S2PM  60932096ULL                  // [8][128][256][2] u64   = 4194304
#define OFF_S3    65126400ULL                  // [8][128][16384] bf16   = 33554432
#define OFF_PRE4P 98680832ULL                  // [8][1024][512] f32     = 16777216
#define OFF_FEAT  115458048ULL                 // [128][512] f32         = 262144
#define OFF_PN    115720192ULL                 // [10][512] f32          = 20480

// ---------------- weight repack + 3-way bf16 split (hi/mid/lo) ----------------
__global__ void repack_w2s(const float* __restrict__ w2, unsigned short* __restrict__ out) {
    int i = blockIdx.x * 256 + threadIdx.x;   // 73728
    if (i >= 73728) return;
    int oc = i / 576, rem = i % 576;
    int ic = rem / 9, tap = rem % 9;
    float w = w2[i];
    unsigned short hi = f2bf(w);  float r1 = w - bf2f(hi);
    unsigned short md = f2bf(r1); float r2 = r1 - bf2f(md);
    unsigned short lo = f2bf(r2);
    size_t base = ((size_t)(tap * 128 + oc)) * 64 + (((ic >> 3) ^ (oc & 7)) << 3) + (ic & 7);
    out[base] = hi; out[base + 73728] = md; out[base + 147456] = lo;
}
__global__ void repack_w3s(const float* __restrict__ w3, unsigned short* __restrict__ out) {
    int i = blockIdx.x * 256 + threadIdx.x;   // 294912
    if (i >= 294912) return;
    int oc = i / 1152, rem = i % 1152;
    int ic = rem / 9, tap = rem % 9;
    float w = w3[i];
    unsigned short hi = f2bf(w);  float r1 = w - bf2f(hi);
    unsigned short md = f2bf(r1); float r2 = r1 - bf2f(md);
    unsigned short lo = f2bf(r2);
    int cc = tap * 2 + (ic >> 6), icl = ic & 63;
    size_t base = ((size_t)(cc * 256 + oc)) * 64 + (((icl >> 3) ^ (oc & 7)) << 3) + (icl & 7);
    out[base] = hi; out[base + 294912] = md; out[base + 589824] = lo;
}
__global__ void repack_fcs(const float* __restrict__ fw, unsigned short* __restrict__ out) {
    int i = blockIdx.x * 256 + threadIdx.x;   // 8388608
    if (i >= 8388608) return;
    int f = i >> 14, d = i & 16383;
    float w = fw[i];
    unsigned short hi = f2bf(w);  float r1 = w - bf2f(hi);
    unsigned short md = f2bf(r1); float r2 = r1 - bf2f(md);
    unsigned short lo = f2bf(r2);
    int cc = d >> 6, kl = d & 63;
    size_t base = (((size_t)cc << 9) + f) * 64 + (((kl >> 3) ^ (f & 7)) << 3) + (kl & 7);
    out[base] = hi; out[base + 8388608] = md; out[base + 16777216] = lo;
}

// ---------------- conv1 + BN + LIF via LDS halo tile ----------------
// block = (b, row y); wave = 8-pixel strip of the row; lane = oc.
__global__ __launch_bounds__(256) void conv1_lif_pack(
    const float* __restrict__ x, const float* __restrict__ w1,
    const float* __restrict__ g1, const float* __restrict__ b1,
    const float* __restrict__ m1, const float* __restrict__ var1,
    unsigned long long* __restrict__ s1m)
{
    __shared__ float xt[3][3][40];   // [ic][row y-1..y+1][col+4], zero-padded halo
    int blk = blockIdx.x;            // 128*32
    int b = blk >> 5, y = blk & 31;
    int tid = threadIdx.x;
    int w = tid >> 6, lane = tid & 63;

    float wr[27];
#pragma unroll
    for (int j = 0; j < 27; ++j) wr[j] = w1[lane * 27 + j];
    float scale = g1[lane] / sqrtf(var1[lane] + EPS);
    float bias  = b1[lane] - m1[lane] * scale;

    float v[8];
#pragma unroll
    for (int p = 0; p < 8; ++p) v[p] = 0.f;

    for (int t = 0; t < 8; ++t) {
        __syncthreads();
        const float* xb = x + ((size_t)(t * 128 + b)) * 3072;
        for (int i = tid; i < 360; i += 256) {
            int ic = i / 120, rem = i % 120, dr = rem / 40, col = rem % 40;
            int yy = y + dr - 1, xx = col - 4;
            float val = 0.f;
            if (yy >= 0 && yy < 32 && xx >= 0 && xx < 32)
                val = xb[ic * 1024 + yy * 32 + xx];
            xt[ic][dr][col] = val;
        }
        __syncthreads();

        float acc[8];
#pragma unroll
        for (int p = 0; p < 8; ++p) acc[p] = 0.f;
#pragma unroll
        for (int ic = 0; ic < 3; ++ic)
#pragma unroll
        for (int dr = 0; dr < 3; ++dr) {
            const float* row = &xt[ic][dr][w * 8];
            float bf[16];
            *(float4*)&bf[0]  = *(const float4*)&row[0];
            *(float4*)&bf[4]  = *(const float4*)&row[4];
            *(float4*)&bf[8]  = *(const float4*)&row[8];
            *(float4*)&bf[12] = *(const float4*)&row[12];
#pragma unroll
            for (int p = 0; p < 8; ++p)
#pragma unroll
                for (int dxm = 0; dxm < 3; ++dxm)
                    acc[p] += bf[p + dxm + 3] * wr[ic * 9 + dr * 3 + dxm];
        }
        size_t base = ((size_t)t * 128 + b) * 1024 + y * 32 + w * 8;
#pragma unroll
        for (int p = 0; p < 8; ++p) {
            float pre = acc[p] * scale + bias;
            v[p] = v[p] + (pre - v[p]) * 0.5f;
            bool s = (v[p] >= 1.0f);
            unsigned long long mk = __ballot(s);
            if (s) v[p] = 0.f;
            if (lane == 0) s1m[base + p] = mk;
        }
    }
}

// ---------------- conv2 MFMA GEMM + BN + LIF + pool, ALL timesteps (v in regs) ----------------
__global__ __launch_bounds__(256, 2) void conv2_mfma(
    const unsigned long long* __restrict__ s1m,   // [8][128][1024]
    const unsigned short* __restrict__ w2s,
    const float* __restrict__ g, const float* __restrict__ bb,
    const float* __restrict__ mm, const float* __restrict__ vv,
    unsigned long long* __restrict__ s2pm)        // [8][128][256][2]
{
    __shared__ unsigned short A[128 * 64];
    __shared__ unsigned short B[3 * 128 * 64];
    __shared__ unsigned long long mt[6][34];
    __shared__ unsigned short pm16[2][16][8];

    int tid = threadIdx.x;
    int m0 = blockIdx.x << 7;
    int b = m0 >> 10;
    int pix0 = m0 & 1023;
    int y0 = pix0 >> 5;

    int w = tid >> 6, lane = tid & 63;
    int wm = w & 1, wn = w >> 1;
    int q = lane >> 4, r = lane & 15;
    int swr = r & 7;
    int am = tid >> 1, ah = tid & 1;
    int ay = am >> 5, ax = am & 31;
    int asw = am & 7;

    float scl[4], bia[4];
#pragma unroll
    for (int j = 0; j < 4; ++j) {
        int oc = wn * 64 + j * 16 + r;
        float s0 = g[oc] / sqrtf(vv[oc] + EPS);
        scl[j] = s0;
        bia[j] = bb[oc] - mm[oc] * s0;
    }

    float vr[4][4][4];
#pragma unroll
    for (int i = 0; i < 4; ++i)
#pragma unroll
        for (int j = 0; j < 4; ++j)
#pragma unroll
            for (int k = 0; k < 4; ++k) vr[i][j][k] = 0.f;

    const char* w2sb = (const char*)w2s;

    for (int t = 0; t < 8; ++t) {
        // stage spike-mask halo for this t (tap-0 leading barrier makes it visible)
        for (int i = tid; i < 204; i += 256) {
            int ly = i / 34, lx = i % 34;
            int yy = y0 + ly - 1, xx = lx - 1;
            unsigned long long mv = 0ULL;
            if (yy >= 0 && yy < 32 && xx >= 0 && xx < 32)
                mv = s1m[(size_t)t * 131072 + (b << 10) + (yy << 5) + xx];
            mt[ly][lx] = mv;
        }

        f32x4 acc[4][4];
#pragma unroll
        for (int i = 0; i < 4; ++i)
#pragma unroll
            for (int j = 0; j < 4; ++j) acc[i][j] = (f32x4){0.f, 0.f, 0.f, 0.f};

        for (int tap = 0; tap < 9; ++tap) {
            int dy = tap / 3, dx = tap - dy * 3;
            __syncthreads();
            {   // build A-tile from bitmask
                unsigned long long mk = mt[ay + dy][ax + dx];
                unsigned int wbits = (unsigned int)(mk >> (ah << 5));
#pragma unroll
                for (int c4 = 0; c4 < 4; ++c4) {
                    unsigned int bt = wbits >> (c4 << 3);
                    uint4 val;
                    val.x = ((bt & 1u) ? 0x3F80u : 0u)  | ((bt & 2u) ? 0x3F800000u : 0u);
                    val.y = ((bt & 4u) ? 0x3F80u : 0u)  | ((bt & 8u) ? 0x3F800000u : 0u);
                    val.z = ((bt & 16u) ? 0x3F80u : 0u) | ((bt & 32u) ? 0x3F800000u : 0u);
                    val.w = ((bt & 64u) ? 0x3F80u : 0u) | ((bt & 128u) ? 0x3F800000u : 0u);
                    int c = (ah << 2) + c4;
                    *(uint4*)((char*)A + am * 128 + ((c ^ asw) << 4)) = val;
                }
            }
            {   // stage B: 3 splits x 16KB
                const char* gb = w2sb + tap * 16384 + (w << 12) + (lane << 4);
                char* lb = (char*)B + (w << 12);
#pragma unroll
                for (int s = 0; s < 3; ++s)
#pragma unroll
                    for (int p = 0; p < 4; ++p)
                        gl_lds16(gb + s * 147456 + (p << 10), lb + s * 16384 + (p << 10));
            }
            __syncthreads();
#pragma unroll
            for (int ks = 0; ks < 2; ++ks) {
                bf16x8 af[4];
#pragma unroll
                for (int i = 0; i < 4; ++i)
                    af[i] = *(const bf16x8*)((const char*)A + (wm * 64 + i * 16 + r) * 128 + ((((ks << 2) + q) ^ swr) << 4));
#pragma unroll
                for (int s = 0; s < 3; ++s) {
                    bf16x8 bfr[4];
#pragma unroll
                    for (int j = 0; j < 4; ++j)
                        bfr[j] = *(const bf16x8*)((const char*)B + s * 16384 + (wn * 64 + j * 16 + r) * 128 + ((((ks << 2) + q) ^ swr) << 4));
#pragma unroll
                    for (int i = 0; i < 4; ++i)
#pragma unroll
                        for (int j = 0; j < 4; ++j)
                            acc[i][j] = __builtin_amdgcn_mfma_f32_16x16x32_bf16(af[i], bfr[j], acc[i][j], 0, 0, 0);
                }
            }
        }

        // epilogue: BN + LIF (v in registers) + 2x2 pool + bitpack
        unsigned long long S = 0ULL;
#pragma unroll
        for (int i = 0; i < 4; ++i) {
#pragma unroll
            for (int j = 0; j < 4; ++j) {
#pragma unroll
                for (int reg = 0; reg < 4; ++reg) {
                    float pre = acc[i][j][reg] * scl[j] + bia[j];
                    float vo = vr[i][j][reg];
                    vo = vo + (pre - vo) * 0.5f;
                    bool sp = (vo >= 1.0f);
                    vr[i][j][reg] = sp ? 0.f : vo;
                    if (sp) S |= 1ULL << (i * 16 + j * 4 + reg);
                }
            }
        }
#pragma unroll
        for (int b1 = 0; b1 < 2; ++b1)
#pragma unroll
            for (int u = 0; u < 2; ++u)
#pragma unroll
                for (int j = 0; j < 4; ++j) {
                    int k0 = b1 * 16 + j * 4 + 2 * u;
                    bool sp = (((S >> k0) | (S >> (k0 + 1)) | (S >> (k0 + 32)) | (S >> (k0 + 33))) & 1ULL) != 0;
                    unsigned long long mk = __ballot(sp);
                    if (r == 0)
                        pm16[wm][b1 * 8 + (q << 1) + u][wn * 4 + j] = (unsigned short)(mk >> (q << 4));
                }
        __syncthreads();
        if (tid < 64) {
            int py = tid >> 5, px = (tid >> 1) & 15, h = tid & 1;
            unsigned long long vmk = *(unsigned long long*)&pm16[py][px][h << 2];
            s2pm[(size_t)t * 65536 + ((size_t)(b << 8) + ((y0 >> 1) + py) * 16 + px) * 2 + h] = vmk;
        }
    }
}

// ---------------- conv3 MFMA GEMM + BN + LIF + pool, ALL timesteps (v in regs) ----------------
__global__ __launch_bounds__(256, 2) void conv3_mfma(
    const unsigned long long* __restrict__ s2pm,  // [8][128][256][2]
    const unsigned short* __restrict__ w3s,
    const float* __restrict__ g, const float* __restrict__ bb,
    const float* __restrict__ mm, const float* __restrict__ vv,
    unsigned short* __restrict__ s3)              // [8][128][16384] bf16, swizzled
{
    __shared__ unsigned short A[128 * 64];
    __shared__ unsigned short B[3 * 128 * 64];
    __shared__ unsigned long long mt3[10][18][2];

    int tid = threadIdx.x;
    int m0 = blockIdx.x << 7;
    int n0 = blockIdx.y << 7;
    int b = m0 >> 8;
    int pix0 = m0 & 255;
    int y0 = pix0 >> 4;     // 0 or 8

    int w = tid >> 6, lane = tid & 63;
    int wm = w & 1, wn = w >> 1;
    int q = lane >> 4, r = lane & 15;
    int swr = r & 7;
    int am = tid >> 1, ah = tid & 1;
    int ay = am >> 4, ax = am & 15;
    int asw = am & 7;

    float scl[4], bia[4];
#pragma unroll
    for (int j = 0; j < 4; ++j) {
        int oc = n0 + wn * 64 + j * 16 + r;
        float s0 = g[oc] / sqrtf(vv[oc] + EPS);
        scl[j] = s0;
        bia[j] = bb[oc] - mm[oc] * s0;
    }

    float vr[4][4][4];
#pragma unroll
    for (int i = 0; i < 4; ++i)
#pragma unroll
        for (int j = 0; j < 4; ++j)
#pragma unroll
            for (int k = 0; k < 4; ++k) vr[i][j][k] = 0.f;

    const char* w3sb = (const char*)w3s;
    int bsw = b & 7;

    for (int t = 0; t < 8; ++t) {
        for (int i = tid; i < 180; i += 256) {
            int ly = i / 18, lx = i % 18;
            int yy = y0 + ly - 1, xx = lx - 1;
            unsigned long long v0 = 0ULL, v1 = 0ULL;
            if (yy >= 0 && yy < 16 && xx >= 0 && xx < 16) {
                const unsigned long long* p = &s2pm[(size_t)t * 65536 + ((size_t)(b << 8) + (yy << 4) + xx) * 2];
                v0 = p[0]; v1 = p[1];
            }
            mt3[ly][lx][0] = v0; mt3[ly][lx][1] = v1;
        }

        f32x4 acc[4][4];
#pragma unroll
        for (int i = 0; i < 4; ++i)
#pragma unroll
            for (int j = 0; j < 4; ++j) acc[i][j] = (f32x4){0.f, 0.f, 0.f, 0.f};

        for (int cc = 0; cc < 18; ++cc) {
            int tap = cc >> 1, h = cc & 1;
            int dy = tap / 3, dx = tap - dy * 3;
            __syncthreads();
            {
                unsigned long long mk = mt3[ay + dy][ax + dx][h];
                unsigned int wbits = (unsigned int)(mk >> (ah << 5));
#pragma unroll
                for (int c4 = 0; c4 < 4; ++c4) {
                    unsigned int bt = wbits >> (c4 << 3);
                    uint4 val;
                    val.x = ((bt & 1u) ? 0x3F80u : 0u)  | ((bt & 2u) ? 0x3F800000u : 0u);
                    val.y = ((bt & 4u) ? 0x3F80u : 0u)  | ((bt & 8u) ? 0x3F800000u : 0u);
                    val.z = ((bt & 16u) ? 0x3F80u : 0u) | ((bt & 32u) ? 0x3F800000u : 0u);
                    val.w = ((bt & 64u) ? 0x3F80u : 0u) | ((bt & 128u) ? 0x3F800000u : 0u);
                    int c = (ah << 2) + c4;
                    *(uint4*)((char*)A + am * 128 + ((c ^ asw) << 4)) = val;
                }
            }
            {
                const char* gb = w3sb + cc * 32768 + n0 * 128 + (w << 12) + (lane << 4);
                char* lb = (char*)B + (w << 12);
#pragma unroll
                for (int s = 0; s < 3; ++s)
#pragma unroll
                    for (int p = 0; p < 4; ++p)
                        gl_lds16(gb + s * 589824 + (p << 10), lb + s * 16384 + (p << 10));
            }
            __syncthreads();
#pragma unroll
            for (int ks = 0; ks < 2; ++ks) {
                bf16x8 af[4];
#pragma unroll
                for (int i = 0; i < 4; ++i)
                    af[i] = *(const bf16x8*)((const char*)A + (wm * 64 + i * 16 + r) * 128 + ((((ks << 2) + q) ^ swr) << 4));
#pragma unroll
                for (int s = 0; s < 3; ++s) {
                    bf16x8 bfr[4];
#pragma unroll
                    for (int j = 0; j < 4; ++j)
                        bfr[j] = *(const bf16x8*)((const char*)B + s * 16384 + (wn * 64 + j * 16 + r) * 128 + ((((ks << 2) + q) ^ swr) << 4));
#pragma unroll
                    for (int i = 0; i < 4; ++i)
#pragma unroll
                        for (int j = 0; j < 4; ++j)
                            acc[i][j] = __builtin_amdgcn_mfma_f32_16x16x32_bf16(af[i], bfr[j], acc[i][j], 0, 0, 0);
                }
            }
        }

        unsigned long long S = 0ULL;
#pragma unroll
        for (int i = 0; i < 4; ++i) {
#pragma unroll
            for (int j = 0; j < 4; ++j) {
#pragma unroll
                for (int reg = 0; reg < 4; ++reg) {
                    float pre = acc[i][j][reg] * scl[j] + bia[j];
                    float vo = vr[i][j][reg];
                    vo = vo + (pre - vo) * 0.5f;
                    bool sp = (vo >= 1.0f);
                    vr[i][j][reg] = sp ? 0.f : vo;
                    if (sp) S |= 1ULL << (i * 16 + j * 4 + reg);
                }
            }
        }
        unsigned short* s3t = s3 + (size_t)t * 2097152;
#pragma unroll
        for (int a2 = 0; a2 < 2; ++a2)
#pragma unroll
            for (int u = 0; u < 2; ++u)
#pragma unroll
                for (int j = 0; j < 4; ++j) {
                    int kA = 32 * a2 + j * 4 + 2 * u;
                    bool sp = (((S >> kA) | (S >> (kA + 1)) | (S >> (kA + 16)) | (S >> (kA + 17))) & 1ULL) != 0;
                    int oc = n0 + wn * 64 + j * 16 + r;
                    int y2 = (y0 >> 1) + wm * 2 + a2;
                    int x2 = (q << 1) + u;
                    s3t[(size_t)(b << 14) + oc * 64 + ((y2 ^ bsw) << 3) + x2] =
                        (unsigned short)(sp ? 0x3F80 : 0);
                }
    }
}

// ---------------- FC MFMA GEMM, split-K into 8 deterministic partials ----------------
__global__ __launch_bounds__(256, 2) void fc_mfma(
    const unsigned short* __restrict__ s3,    // [1024][16384] bf16, swizzled by (m&7)
    const unsigned short* __restrict__ fcs,
    float* __restrict__ pre4p)                // [8][1024][512]
{
    __shared__ unsigned short A[128 * 64];
    __shared__ unsigned short B[3 * 128 * 64];

    int tid = threadIdx.x;
    int m0 = blockIdx.x << 7;
    int n0 = blockIdx.y << 7;
    int kseg = blockIdx.z;
    int cc0 = kseg << 5;

    int w = tid >> 6, lane = tid & 63;
    int wm = w & 1, wn = w >> 1;
    int q = lane >> 4, r = lane & 15;
    int swr = r & 7;

    f32x4 acc[4][4];
#pragma unroll
    for (int i = 0; i < 4; ++i)
#pragma unroll
        for (int j = 0; j < 4; ++j) acc[i][j] = (f32x4){0.f, 0.f, 0.f, 0.f};

    const char* s3b = (const char*)s3;
    const char* fcsb = (const char*)fcs;

    for (int cc = cc0; cc < cc0 + 32; ++cc) {
        __syncthreads();
        {
            char* lb = (char*)A + (w << 12);
#pragma unroll
            for (int p = 0; p < 4; ++p)
                gl_lds16(s3b + (size_t)(m0 + w * 32 + p * 8 + (lane >> 3)) * 32768
                             + cc * 128 + ((lane & 7) << 4),
                         lb + (p << 10));
        }
        {
            const char* gb = fcsb + cc * 65536 + n0 * 128 + (w << 12) + (lane << 4);
            char* lb = (char*)B + (w << 12);
#pragma unroll
            for (int s = 0; s < 3; ++s)
#pragma unroll
                for (int p = 0; p < 4; ++p)
                    gl_lds16(gb + s * 16777216 + (p << 10), lb + s * 16384 + (p << 10));
        }
        __syncthreads();
#pragma unroll
        for (int ks = 0; ks < 2; ++ks) {
            bf16x8 af[4];
#pragma unroll
            for (int i = 0; i < 4; ++i)
                af[i] = *(const bf16x8*)((const char*)A + (wm * 64 + i * 16 + r) * 128 + ((((ks << 2) + q) ^ swr) << 4));
#pragma unroll
            for (int s = 0; s < 3; ++s) {
                bf16x8 bfr[4];
#pragma unroll
                for (int j = 0; j < 4; ++j)
                    bfr[j] = *(const bf16x8*)((const char*)B + s * 16384 + (wn * 64 + j * 16 + r) * 128 + ((((ks << 2) + q) ^ swr) << 4));
#pragma unroll
                for (int i = 0; i < 4; ++i)
#pragma unroll
                    for (int j = 0; j < 4; ++j)
                        acc[i][j] = __builtin_amdgcn_mfma_f32_16x16x32_bf16(af[i], bfr[j], acc[i][j], 0, 0, 0);
            }
        }
    }
#pragma unroll
    for (int i = 0; i < 4; ++i) {
#pragma unroll
        for (int j = 0; j < 4; ++j) {
            size_t base = ((size_t)kseg * 1024 + m0 + wm * 64 + i * 16 + (q << 2)) * 512
                        + n0 + wn * 64 + j * 16 + r;
#pragma unroll
            for (int reg = 0; reg < 4; ++reg)
                pre4p[base + (size_t)reg * 512] = acc[i][j][reg];
        }
    }
}

// ---------------- LIF over FC output (sum 8 partials deterministically) + mean ----------------
__global__ void lif4_mean(const float* __restrict__ P, float* __restrict__ feat) {
    int i = blockIdx.x * 256 + threadIdx.x;
    if (i >= 65536) return;
    int b = i >> 9, f = i & 511;
    float v = 0.f, sum = 0.f;
#pragma unroll
    for (int t = 0; t < 8; ++t) {
        float pre = 0.f;
#pragma unroll
        for (int s = 0; s < 8; ++s)
            pre += P[(size_t)s * 524288 + (size_t)(t * 128 + b) * 512 + f];
        v = v + (pre - v) * 0.5f;
        if (v >= 1.0f) { sum += 1.f; v = 0.f; }
    }
    feat[i] = sum * 0.125f;
}

__global__ void protos_norm(const float* __restrict__ P, float* __restrict__ pn) {
    int p = blockIdx.x;
    int lane = threadIdx.x;
    float ss = 0.f;
    for (int f = lane; f < 512; f += 64) { float x = P[p * 512 + f]; ss += x * x; }
#pragma unroll
    for (int o = 32; o > 0; o >>= 1) ss += __shfl_xor(ss, o);
    float inv = 1.f / fmaxf(sqrtf(ss), 1e-12f);
    for (int f = lane; f < 512; f += 64) pn[p * 512 + f] = P[p * 512 + f] * inv;
}

__global__ void final_logits(const float* __restrict__ feat, const float* __restrict__ pn,
                             float* __restrict__ out) {
    int b = blockIdx.x;
    int lane = threadIdx.x;
    float fr[8];
    float ss = 0.f;
#pragma unroll
    for (int j = 0; j < 8; ++j) { fr[j] = feat[b * 512 + j * 64 + lane]; ss += fr[j] * fr[j]; }
#pragma unroll
    for (int o = 32; o > 0; o >>= 1) ss += __shfl_xor(ss, o);
    float inv = 10.f / fmaxf(sqrtf(ss), 1e-12f);
    for (int p = 0; p < 10; ++p) {
        float d = 0.f;
#pragma unroll
        for (int j = 0; j < 8; ++j) d += fr[j] * pn[p * 512 + j * 64 + lane];
#pragma unroll
        for (int o = 32; o > 0; o >>= 1) d += __shfl_xor(d, o);
        if (lane == 0) out[b * 10 + p] = d * inv;
    }
}

extern "C" void kernel_launch(void* const* d_in, const int* in_sizes, int n_in,
                              void* d_out, int out_size, void* d_ws, size_t ws_size,
                              hipStream_t stream) {
    const float* x      = (const float*)d_in[0];
    const float* w1     = (const float*)d_in[1];
    const float* w2     = (const float*)d_in[2];
    const float* w3     = (const float*)d_in[3];
    const float* fc1    = (const float*)d_in[4];
    const float* protos = (const float*)d_in[5];
    const float* g1 = (const float*)d_in[6],  *b1 = (const float*)d_in[7];
    const float* m1 = (const float*)d_in[8],  *v1 = (const float*)d_in[9];
    const float* g2 = (const float*)d_in[10], *b2 = (const float*)d_in[11];
    const float* m2 = (const float*)d_in[12], *v2p = (const float*)d_in[13];
    const float* g3 = (const float*)d_in[14], *b3 = (const float*)d_in[15];
    const float* m3 = (const float*)d_in[16], *v3p = (const float*)d_in[17];

    char* ws = (char*)d_ws;
    unsigned short* w2s = (unsigned short*)(ws + OFF_W2S);
    unsigned short* w3s = (unsigned short*)(ws + OFF_W3S);
    unsigned short* fcs = (unsigned short*)(ws + OFF_FCS);
    unsigned long long* s1m  = (unsigned long long*)(ws + OFF_S1M);
    unsigned long long* s2pm = (unsigned long long*)(ws + OFF_S2PM);
    unsigned short* s3 = (unsigned short*)(ws + OFF_S3);
    float* pre4p = (float*)(ws + OFF_PRE4P);
    float* feat  = (float*)(ws + OFF_FEAT);
    float* pn    = (float*)(ws + OFF_PN);

    repack_w2s<<<288, 256, 0, stream>>>(w2, w2s);
    repack_w3s<<<1152, 256, 0, stream>>>(w3, w3s);
    repack_fcs<<<32768, 256, 0, stream>>>(fc1, fcs);

    conv1_lif_pack<<<4096, 256, 0, stream>>>(x, w1, g1, b1, m1, v1, s1m);
    conv2_mfma<<<1024, 256, 0, stream>>>(s1m, w2s, g2, b2, m2, v2p, s2pm);
    conv3_mfma<<<dim3(256, 2), 256, 0, stream>>>(s2pm, w3s, g3, b3, m3, v3p, s3);

    fc_mfma<<<dim3(8, 4, 8), 256, 0, stream>>>(s3, fcs, pre4p);
    lif4_mean<<<256, 256, 0, stream>>>(pre4p, feat);
    protos_norm<<<10, 64, 0, stream>>>(protos, pn);
    final_logits<<<128, 64, 0, stream>>>(feat, pn, (float*)d_out);
}